// Round 21
// baseline (158.878 us; speedup 1.0000x reference)
//
#include <hip/hip_runtime.h>

#define EMBED 1024
#define C3    3072
#define NHEAD 16
#define HDIM  64
#define BB    4
#define TT    2048
#define MTOK  8192   // BB*TT

typedef __bf16 bf16;
typedef __bf16 bf16x4 __attribute__((ext_vector_type(4)));
typedef __bf16 bf16x8 __attribute__((ext_vector_type(8)));
typedef float  f32x4  __attribute__((ext_vector_type(4)));
typedef float  f32x16 __attribute__((ext_vector_type(16)));
typedef unsigned int u32;

__device__ __forceinline__ void gload_lds16(const bf16* g, bf16* l) {
  __builtin_amdgcn_global_load_lds((__attribute__((address_space(1))) void*)g,
                                   (__attribute__((address_space(3))) void*)l,
                                   16, 0, 0);
}

__device__ __forceinline__ u32 pkbf(float lo, float hi_) {
  union { bf16 h[2]; u32 w; } u;
  u.h[0] = (bf16)lo; u.h[1] = (bf16)hi_;
  return u.w;
}

union upw { u32 w[4]; bf16x8 v; };

// ---------------- fused fp32 -> bf16 convert ----------------
__global__ __launch_bounds__(256) void cvt_all(const float* __restrict__ x,
                                               const float* __restrict__ w1,
                                               const float* __restrict__ w2,
                                               bf16* __restrict__ xb,
                                               bf16* __restrict__ wqkv,
                                               bf16* __restrict__ wproj) {
  const int N1 = MTOK * EMBED, N2 = C3 * EMBED, N3 = EMBED * EMBED;
  int i = (blockIdx.x * blockDim.x + threadIdx.x) * 4;
  const float* src; bf16* dst;
  if (i < N1)           { src = x + i;            dst = xb + i; }
  else if (i < N1 + N2) { src = w1 + (i - N1);    dst = wqkv + (i - N1); }
  else if (i < N1 + N2 + N3) { src = w2 + (i - N1 - N2); dst = wproj + (i - N1 - N2); }
  else return;
  float4 v = *reinterpret_cast<const float4*>(src);
  bf16x4 o;
  o[0] = (bf16)v.x; o[1] = (bf16)v.y; o[2] = (bf16)v.z; o[3] = (bf16)v.w;
  *reinterpret_cast<bf16x4*>(dst) = o;
}

// ================= GEMM core (R16/R18: BK=64, swizzled LDS, hoisted, 1-buffer) =====
__device__ __forceinline__ void gemm_core(const bf16* __restrict__ A,
                                          const bf16* __restrict__ W,
                                          bf16* lA, bf16* lB,
                                          int K, int bm0, int bn0,
                                          int wm, int wn, int l15, int lg,
                                          f32x4 (&acc)[4][4]) {
  const int tid  = threadIdx.x;
  const int grow = tid >> 3;
  const int gseg = tid & 7;

  const bf16* srcA[4];
  const bf16* srcB[4];
#pragma unroll
  for (int r = 0; r < 4; ++r) {
    const int row = r * 32 + grow;
    const int seg = gseg ^ (row & 7);
    srcA[r] = A + (size_t)(bm0 + row) * K + seg * 8;
    srcB[r] = W + (size_t)(bn0 + row) * K + seg * 8;
  }
  int offA[2][4], offB[2][4];
#pragma unroll
  for (int kk = 0; kk < 2; ++kk) {
#pragma unroll
    for (int i = 0; i < 4; ++i) {
      const int rowA = wm + i * 16 + l15;
      const int rowB = wn + i * 16 + l15;
      offA[kk][i] = rowA * 128 + ((kk * 64 + lg * 16) ^ ((rowA & 7) << 4));
      offB[kk][i] = rowB * 128 + ((kk * 64 + lg * 16) ^ ((rowB & 7) << 4));
    }
  }

  for (int kt = 0; kt < K; kt += 64) {
#pragma unroll
    for (int r = 0; r < 4; ++r) {
      gload_lds16(srcA[r] + kt, &lA[(r * 256 + tid) * 8]);
      gload_lds16(srcB[r] + kt, &lB[(r * 256 + tid) * 8]);
    }
    __syncthreads();
    const char* Ab = (const char*)lA;
    const char* Bb = (const char*)lB;
#pragma unroll
    for (int kk = 0; kk < 2; ++kk) {
      bf16x8 af[4], bf_[4];
#pragma unroll
      for (int i = 0; i < 4; ++i) af[i]  = *reinterpret_cast<const bf16x8*>(Ab + offA[kk][i]);
#pragma unroll
      for (int j = 0; j < 4; ++j) bf_[j] = *reinterpret_cast<const bf16x8*>(Bb + offB[kk][j]);
#pragma unroll
      for (int i = 0; i < 4; ++i)
#pragma unroll
        for (int j = 0; j < 4; ++j)
          acc[i][j] = __builtin_amdgcn_mfma_f32_16x16x32_bf16(af[i], bf_[j],
                                                              acc[i][j], 0, 0, 0);
    }
    __syncthreads();
  }
}

// ---------------- GEMM1: qkv = x @ qkv_w^T + b, per-head layouts, XCD-tiled --------
__global__ __launch_bounds__(256) void gemm_qkv(const bf16* __restrict__ A,
                                                const bf16* __restrict__ W,
                                                const float* __restrict__ bias,
                                                bf16* __restrict__ Qh,
                                                bf16* __restrict__ Kh,
                                                bf16* __restrict__ VhT) {
  __shared__ __align__(16) bf16 lA[128 * 64];
  __shared__ __align__(16) bf16 lB[128 * 64];
  const int tid  = threadIdx.x;
  const int lane = tid & 63, wave = tid >> 6;
  const int wm   = (wave >> 1) * 64;
  const int wn   = (wave & 1) * 64;
  const int bidx = blockIdx.x;
  const int g  = bidx & 7;
  const int i_ = bidx >> 3;                 // 0..191
  const int bm0 = (g * 8 + (i_ & 7)) * 128;
  const int bn0 = (i_ >> 3) * 128;          // 0..23
  const int l15  = lane & 15, lg = lane >> 4;

  f32x4 acc[4][4] = {};
  gemm_core(A, W, lA, lB, EMBED, bm0, bn0, wm, wn, l15, lg, acc);

  const int sec = bn0 >> 10;   // 0=Q 1=K 2=V, uniform per block
  const int hh  = ((bn0 + wn) & 1023) >> 6;
  const int rw0 = bm0 + wm;
  const int bb  = rw0 >> 11, t00 = rw0 & 2047;
  const int bh  = bb * 16 + hh;

  if (sec < 2) {
    bf16* ep = ((wave < 2) ? lA : lB) + (wave & 1) * 4096;   // 64x64 bf16 per wave
#pragma unroll
    for (int i = 0; i < 4; ++i)
#pragma unroll
      for (int j = 0; j < 4; ++j) {
        const float bs = bias[bn0 + wn + j * 16 + l15];
        const int cj = j * 16 + l15;
#pragma unroll
        for (int r = 0; r < 4; ++r) {
          const int ri = i * 16 + 4 * lg + r;
          ep[ri * 64 + (cj ^ ((ri & 7) << 3))] = (bf16)(acc[i][j][r] + bs);
        }
      }
    __syncthreads();
    bf16* dstB = (sec ? Kh : Qh) + ((size_t)bh * TT + t00) * HDIM;
    const int seg = lane & 7;
#pragma unroll
    for (int k = 0; k < 8; ++k) {
      const int ri = k * 8 + (lane >> 3);
      bf16x8 v = *reinterpret_cast<const bf16x8*>(&ep[ri * 64 + ((seg ^ (ri & 7)) * 8)]);
      *reinterpret_cast<bf16x8*>(dstB + (size_t)ri * HDIM + seg * 8) = v;
    }
  } else {
#pragma unroll
    for (int i = 0; i < 4; ++i)
#pragma unroll
      for (int j = 0; j < 4; ++j) {
        const int col = bn0 + wn + j * 16 + l15;
        const float bs = bias[col];
        const int dd = col & 63;
        const int t0 = t00 + i * 16 + lg * 4;
        bf16x4 o4;
#pragma unroll
        for (int r = 0; r < 4; ++r) o4[r] = (bf16)(acc[i][j][r] + bs);
        *reinterpret_cast<bf16x4*>(VhT + ((size_t)bh * HDIM + dd) * TT + t0) = o4;
      }
  }
}

// ---------------- GEMM2: out = A @ W^T + b (fp32 out), XCD-tiled -------------------
__global__ __launch_bounds__(256) void gemm_bt(const bf16* __restrict__ A,
                                               const bf16* __restrict__ W,
                                               const float* __restrict__ bias,
                                               float* __restrict__ Cf,
                                               int M, int N, int K) {
  __shared__ __align__(16) bf16 lA[128 * 64];
  __shared__ __align__(16) bf16 lB[128 * 64];
  const int tid  = threadIdx.x;
  const int lane = tid & 63, wave = tid >> 6;
  const int wm   = (wave >> 1) * 64;
  const int wn   = (wave & 1) * 64;
  const int bidx = blockIdx.x;
  const int g  = bidx & 7;
  const int i_ = bidx >> 3;                 // 0..63
  const int bm0 = (g * 8 + (i_ & 7)) * 128;
  const int bn0 = (i_ >> 3) * 128;          // 0..7
  const int l15  = lane & 15, lg = lane >> 4;

  f32x4 acc[4][4] = {};
  gemm_core(A, W, lA, lB, K, bm0, bn0, wm, wn, l15, lg, acc);

#pragma unroll
  for (int i = 0; i < 4; ++i)
#pragma unroll
    for (int j = 0; j < 4; ++j) {
      int col = bn0 + wn + j * 16 + l15;
      float bs = bias[col];
#pragma unroll
      for (int r = 0; r < 4; ++r) {
        int row = bm0 + wm + i * 16 + lg * 4 + r;
        Cf[(size_t)row * N + col] = acc[i][j][r] + bs;
      }
    }
}

// ---------------- one 32q x 64kv attention tile (R10-verified math) ----------------
__device__ __forceinline__ void attn_tile(const char* kbase, const char* vbase,
                                          const bf16x8 (&qfr)[4], f32x16 (&oacc)[2],
                                          float& mrun, float& srun,
                                          const int kv0, const int q0w,
                                          const int l31, const int hi, const int swz) {
  f32x16 s0 = {}, s1 = {};
  __builtin_amdgcn_s_setprio(1);
#pragma unroll
  for (int dc = 0; dc < 4; ++dc) {
    bf16x8 kf = *reinterpret_cast<const bf16x8*>(
        kbase + l31 * 128 + (((2 * dc + hi) * 16) ^ swz));
    s0 = __builtin_amdgcn_mfma_f32_32x32x16_bf16(kf, qfr[dc], s0, 0, 0, 0);
  }
#pragma unroll
  for (int dc = 0; dc < 4; ++dc) {
    bf16x8 kf = *reinterpret_cast<const bf16x8*>(
        kbase + (32 + l31) * 128 + (((2 * dc + hi) * 16) ^ swz));
    s1 = __builtin_amdgcn_mfma_f32_32x32x16_bf16(kf, qfr[dc], s1, 0, 0, 0);
  }
  __builtin_amdgcn_s_setprio(0);

  if (kv0 + 63 > q0w) {
    const int qg = q0w + l31;
#pragma unroll
    for (int r = 0; r < 16; ++r) {
      const int kvb = kv0 + (r & 3) + 8 * (r >> 2) + 4 * hi;
      if (kvb > qg)      s0[r] = -3e38f;
      if (kvb + 32 > qg) s1[r] = -3e38f;
    }
  }

  float m8[8];
#pragma unroll
  for (int i = 0; i < 8; ++i)
    m8[i] = fmaxf(fmaxf(s0[i], s0[i + 8]), fmaxf(s1[i], s1[i + 8]));
#pragma unroll
  for (int st = 4; st > 0; st >>= 1)
#pragma unroll
    for (int i = 0; i < st; ++i) m8[i] = fmaxf(m8[i], m8[i + st]);
  float mx = fmaxf(m8[0], __shfl_xor(m8[0], 32));

  float mref = mrun;
  if (!__all(mx <= mrun + 8.0f)) {
    const float mnew = fmaxf(mrun, mx);
    const float corr = __builtin_amdgcn_exp2f(mrun - mnew);
    mrun = mnew; mref = mnew;
    srun *= corr;
#pragma unroll
    for (int r = 0; r < 16; ++r) { oacc[0][r] *= corr; oacc[1][r] *= corr; }
  }

  float psum = 0.0f;
#pragma unroll
  for (int r = 0; r < 16; ++r) {
    s0[r] = __builtin_amdgcn_exp2f(s0[r] - mref);
    s1[r] = __builtin_amdgcn_exp2f(s1[r] - mref);
    psum += s0[r] + s1[r];
  }
  srun += psum;

  upw pw[4];
#pragma unroll
  for (int cl = 0; cl < 2; ++cl) {
    {
      u32 a01 = pkbf(s0[8 * cl + 0], s0[8 * cl + 1]);
      u32 a23 = pkbf(s0[8 * cl + 2], s0[8 * cl + 3]);
      u32 b01 = pkbf(s0[8 * cl + 4], s0[8 * cl + 5]);
      u32 b23 = pkbf(s0[8 * cl + 6], s0[8 * cl + 7]);
      asm("v_permlane32_swap_b32 %0, %1" : "+v"(a01), "+v"(b01));
      asm("v_permlane32_swap_b32 %0, %1" : "+v"(a23), "+v"(b23));
      pw[cl].w[0] = a01; pw[cl].w[1] = a23; pw[cl].w[2] = b01; pw[cl].w[3] = b23;
    }
    {
      u32 a01 = pkbf(s1[8 * cl + 0], s1[8 * cl + 1]);
      u32 a23 = pkbf(s1[8 * cl + 2], s1[8 * cl + 3]);
      u32 b01 = pkbf(s1[8 * cl + 4], s1[8 * cl + 5]);
      u32 b23 = pkbf(s1[8 * cl + 6], s1[8 * cl + 7]);
      asm("v_permlane32_swap_b32 %0, %1" : "+v"(a01), "+v"(b01));
      asm("v_permlane32_swap_b32 %0, %1" : "+v"(a23), "+v"(b23));
      pw[2 + cl].w[0] = a01; pw[2 + cl].w[1] = a23; pw[2 + cl].w[2] = b01; pw[2 + cl].w[3] = b23;
    }
  }

  __builtin_amdgcn_s_setprio(1);
#pragma unroll
  for (int dh = 0; dh < 2; ++dh) {
    const char* vrow = vbase + (32 * dh + l31) * 256;
#pragma unroll
    for (int c = 0; c < 4; ++c) {
      bf16x8 vf = *reinterpret_cast<const bf16x8*>(vrow + (((2 * c + hi) * 16) ^ swz));
      oacc[dh] = __builtin_amdgcn_mfma_f32_32x32x16_bf16(vf, pw[c].v, oacc[dh], 0, 0, 0);
    }
  }
  __builtin_amdgcn_s_setprio(0);
}

// ---------------- causal flash attention: 8-wave band-split, KVBLK=128 -------------
// CU-pairing remap: co-resident blocks bid and bid+256 (same CU under round-robin)
// get complementary H-band lengths -> per-CU work sum is constant (25 tile-units).
__global__ __launch_bounds__(512, 4) void attn_kernel(const bf16* __restrict__ Qh,
                                                      const bf16* __restrict__ Kh,
                                                      const bf16* __restrict__ VhT,
                                                      bf16* __restrict__ aout) {
  __shared__ __align__(16) bf16 lK[2][128 * 64];
  __shared__ __align__(16) bf16 lVT[2][64 * 128];
  const int tid  = threadIdx.x;
  const int lane = tid & 63, wave = tid >> 6;   // 0..7
  const int l31  = lane & 31;
  const int hi   = lane >> 5;
  const int bid  = blockIdx.x;              // 0..511
  const int half = bid >> 8;                // 0 or 1
  const int idx  = bid & 255;
  const int bh   = idx & 63;                // same-bh blocks share an XCD
  const int p    = half ? (7 - (idx >> 6)) : (idx >> 6);   // complementary pairing
  const int qtH  = 15 - p, qtL = p;
  const int band = wave >> 2;               // 0 = H, 1 = L
  const int qt   = band ? qtL : qtH;
  const int q0w  = qt * 128 + (wave & 3) * 32;
  const int b    = bh >> 4, h = bh & 15;
  const size_t tb = (size_t)b * TT;
  const int swz  = (l31 & 7) << 4;

  const float QSCALE = 0.18033688011112042f;
  bf16x8 qfr[4];
  {
    const bf16* qrow = Qh + ((size_t)bh * TT + q0w + l31) * HDIM;
#pragma unroll
    for (int dc = 0; dc < 4; ++dc) {
      bf16x8 v = *reinterpret_cast<const bf16x8*>(qrow + dc * 16 + hi * 8);
      bf16x8 o;
#pragma unroll
      for (int j = 0; j < 8; ++j) o[j] = (bf16)((float)v[j] * QSCALE);
      qfr[dc] = o;
    }
  }

  f32x16 oacc[2] = {};
  float mrun = -3e38f, srun = 0.0f;

  const int r0 = tid >> 3;
  const int sg = tid & 7;
  const int segK = sg ^ (r0 & 7);
  const bf16* kS = Kh + ((size_t)bh * TT + r0) * HDIM + (size_t)segK * 8;
  bf16* kD0 = &lK[0][r0 * 64 + sg * 8];
  bf16* kD1 = &lK[0][(r0 + 64) * 64 + sg * 8];
  const int rv = tid >> 4;
  const int hs = (tid >> 3) & 1;
  const int jv = tid & 7;
  const int cv = jv ^ (rv & 7);
  const bf16* vS0 = VhT + ((size_t)bh * HDIM + rv) * TT + hs * 64 + (size_t)cv * 8;
  const bf16* vS1 = VhT + ((size_t)bh * HDIM + rv + 32) * TT + hs * 64 + (size_t)cv * 8;
  bf16* vD0 = &lVT[0][tid * 8];
  bf16* vD1 = &lVT[0][(tid + 512) * 8];
  const int lKsz = 128 * 64, lVsz = 64 * 128;

  const int nkvt = qtH + 1;

  gload_lds16(kS,             kD0);
  gload_lds16(kS + 64 * HDIM, kD1);
  gload_lds16(vS0,            vD0);
  gload_lds16(vS1,            vD1);
  __syncthreads();

  int cur = 0;
  for (int t = 0; t < nkvt; ++t) {
    if (t + 1 < nkvt) {
      const size_t kv = (size_t)(t + 1) * 128;
      const int bo = (cur ^ 1);
      gload_lds16(kS + kv * HDIM,        kD0 + bo * lKsz);
      gload_lds16(kS + (kv + 64) * HDIM, kD1 + bo * lKsz);
      gload_lds16(vS0 + kv,              vD0 + bo * lVsz);
      gload_lds16(vS1 + kv,              vD1 + bo * lVsz);
    }

#pragma unroll
    for (int s = 0; s < 2; ++s) {
      const int kv0 = t * 128 + s * 64;
      if (kv0 <= q0w + 31)
        attn_tile((const char*)&lK[cur][0] + s * 8192,
                  (const char*)&lVT[cur][0] + s * 128,
                  qfr, oacc, mrun, srun, kv0, q0w, l31, hi, swz);
    }

    __syncthreads();
    cur ^= 1;
  }

  {
    srun += __shfl_xor(srun, 32);
    const float inv = 1.0f / srun;
    const int q = q0w + l31;
    bf16* orow = aout + (tb + q) * (size_t)EMBED + h * HDIM;
#pragma unroll
    for (int dh = 0; dh < 2; ++dh)
#pragma unroll
      for (int rb = 0; rb < 4; ++rb) {
        bf16x4 o4;
#pragma unroll
        for (int k = 0; k < 4; ++k) o4[k] = (bf16)(oacc[dh][4 * rb + k] * inv);
        *reinterpret_cast<bf16x4*>(orow + 32 * dh + 8 * rb + 4 * hi) = o4;
      }
  }
}

extern "C" void kernel_launch(void* const* d_in, const int* in_sizes, int n_in,
                              void* d_out, int out_size, void* d_ws, size_t ws_size,
                              hipStream_t stream) {
  const float* x      = (const float*)d_in[0];
  const float* qkv_w  = (const float*)d_in[1];
  const float* qkv_b  = (const float*)d_in[2];
  const float* proj_w = (const float*)d_in[3];
  const float* proj_b = (const float*)d_in[4];
  float* out = (float*)d_out;

  const size_t QSZ = (size_t)BB * NHEAD * TT * HDIM;
  char* ws = (char*)d_ws;
  bf16* xb    = (bf16*)ws;
  bf16* wqkv  = xb + (size_t)MTOK * EMBED;
  bf16* wproj = wqkv + (size_t)C3 * EMBED;
  bf16* Qh    = wproj + (size_t)EMBED * EMBED;
  bf16* Kh    = Qh + QSZ;
  bf16* VhT   = Kh + QSZ;
  bf16* aob   = xb;   // alias: xb dead after gemm_qkv

  const int NCVT = (MTOK * EMBED + C3 * EMBED + EMBED * EMBED) / 4;
  cvt_all<<<dim3((NCVT + 255) / 256), dim3(256), 0, stream>>>(x, qkv_w, proj_w,
                                                              xb, wqkv, wproj);

  gemm_qkv<<<dim3(1536), dim3(256), 0, stream>>>(xb, wqkv, qkv_b, Qh, Kh, VhT);

  attn_kernel<<<dim3(512), dim3(512), 0, stream>>>(Qh, Kh, VhT, aob);

  gemm_bt<<<dim3(512), dim3(256), 0, stream>>>(aob, wproj, proj_b, out,
                                               MTOK, EMBED, EMBED);
}

// Round 22
// 157.714 us; speedup vs baseline: 1.0074x; 1.0074x over previous
//
#include <hip/hip_runtime.h>

#define EMBED 1024
#define C3    3072
#define NHEAD 16
#define HDIM  64
#define BB    4
#define TT    2048
#define MTOK  8192   // BB*TT

typedef __bf16 bf16;
typedef __bf16 bf16x4 __attribute__((ext_vector_type(4)));
typedef __bf16 bf16x8 __attribute__((ext_vector_type(8)));
typedef float  f32x4  __attribute__((ext_vector_type(4)));
typedef float  f32x16 __attribute__((ext_vector_type(16)));
typedef unsigned int u32;

__device__ __forceinline__ void gload_lds16(const bf16* g, bf16* l) {
  __builtin_amdgcn_global_load_lds((__attribute__((address_space(1))) void*)g,
                                   (__attribute__((address_space(3))) void*)l,
                                   16, 0, 0);
}

__device__ __forceinline__ u32 pkbf(float lo, float hi_) {
  union { bf16 h[2]; u32 w; } u;
  u.h[0] = (bf16)lo; u.h[1] = (bf16)hi_;
  return u.w;
}

union upw { u32 w[4]; bf16x8 v; };

// ---------------- fused fp32 -> bf16 convert (grid-stride, G11) ----------------
__global__ __launch_bounds__(256) void cvt_all(const float* __restrict__ x,
                                               const float* __restrict__ w1,
                                               const float* __restrict__ w2,
                                               bf16* __restrict__ xb,
                                               bf16* __restrict__ wqkv,
                                               bf16* __restrict__ wproj) {
  const int N1 = MTOK * EMBED, N2 = C3 * EMBED, N3 = EMBED * EMBED;
  const int NT = (N1 + N2 + N3) / 4;
  for (int t = blockIdx.x * blockDim.x + threadIdx.x; t < NT;
       t += gridDim.x * blockDim.x) {
    const int i = t * 4;
    const float* src; bf16* dst;
    if (i < N1)           { src = x + i;            dst = xb + i; }
    else if (i < N1 + N2) { src = w1 + (i - N1);    dst = wqkv + (i - N1); }
    else                  { src = w2 + (i - N1 - N2); dst = wproj + (i - N1 - N2); }
    float4 v = *reinterpret_cast<const float4*>(src);
    bf16x4 o;
    o[0] = (bf16)v.x; o[1] = (bf16)v.y; o[2] = (bf16)v.z; o[3] = (bf16)v.w;
    *reinterpret_cast<bf16x4*>(dst) = o;
  }
}

// ================= GEMM core (R16/R18: BK=64, swizzled LDS, hoisted, 1-buffer) =====
__device__ __forceinline__ void gemm_core(const bf16* __restrict__ A,
                                          const bf16* __restrict__ W,
                                          bf16* lA, bf16* lB,
                                          int K, int bm0, int bn0,
                                          int wm, int wn, int l15, int lg,
                                          f32x4 (&acc)[4][4]) {
  const int tid  = threadIdx.x;
  const int grow = tid >> 3;
  const int gseg = tid & 7;

  const bf16* srcA[4];
  const bf16* srcB[4];
#pragma unroll
  for (int r = 0; r < 4; ++r) {
    const int row = r * 32 + grow;
    const int seg = gseg ^ (row & 7);
    srcA[r] = A + (size_t)(bm0 + row) * K + seg * 8;
    srcB[r] = W + (size_t)(bn0 + row) * K + seg * 8;
  }
  int offA[2][4], offB[2][4];
#pragma unroll
  for (int kk = 0; kk < 2; ++kk) {
#pragma unroll
    for (int i = 0; i < 4; ++i) {
      const int rowA = wm + i * 16 + l15;
      const int rowB = wn + i * 16 + l15;
      offA[kk][i] = rowA * 128 + ((kk * 64 + lg * 16) ^ ((rowA & 7) << 4));
      offB[kk][i] = rowB * 128 + ((kk * 64 + lg * 16) ^ ((rowB & 7) << 4));
    }
  }

  for (int kt = 0; kt < K; kt += 64) {
#pragma unroll
    for (int r = 0; r < 4; ++r) {
      gload_lds16(srcA[r] + kt, &lA[(r * 256 + tid) * 8]);
      gload_lds16(srcB[r] + kt, &lB[(r * 256 + tid) * 8]);
    }
    __syncthreads();
    const char* Ab = (const char*)lA;
    const char* Bb = (const char*)lB;
#pragma unroll
    for (int kk = 0; kk < 2; ++kk) {
      bf16x8 af[4], bf_[4];
#pragma unroll
      for (int i = 0; i < 4; ++i) af[i]  = *reinterpret_cast<const bf16x8*>(Ab + offA[kk][i]);
#pragma unroll
      for (int j = 0; j < 4; ++j) bf_[j] = *reinterpret_cast<const bf16x8*>(Bb + offB[kk][j]);
#pragma unroll
      for (int i = 0; i < 4; ++i)
#pragma unroll
        for (int j = 0; j < 4; ++j)
          acc[i][j] = __builtin_amdgcn_mfma_f32_16x16x32_bf16(af[i], bf_[j],
                                                              acc[i][j], 0, 0, 0);
    }
    __syncthreads();
  }
}

// ---------------- GEMM1: qkv = x @ qkv_w^T + b, per-head layouts, XCD-tiled --------
__global__ __launch_bounds__(256) void gemm_qkv(const bf16* __restrict__ A,
                                                const bf16* __restrict__ W,
                                                const float* __restrict__ bias,
                                                bf16* __restrict__ Qh,
                                                bf16* __restrict__ Kh,
                                                bf16* __restrict__ VhT) {
  __shared__ __align__(16) bf16 lA[128 * 64];
  __shared__ __align__(16) bf16 lB[128 * 64];
  const int tid  = threadIdx.x;
  const int lane = tid & 63, wave = tid >> 6;
  const int wm   = (wave >> 1) * 64;
  const int wn   = (wave & 1) * 64;
  const int bidx = blockIdx.x;
  const int g  = bidx & 7;
  const int i_ = bidx >> 3;                 // 0..191
  const int bm0 = (g * 8 + (i_ & 7)) * 128;
  const int bn0 = (i_ >> 3) * 128;          // 0..23
  const int l15  = lane & 15, lg = lane >> 4;

  f32x4 acc[4][4] = {};
  gemm_core(A, W, lA, lB, EMBED, bm0, bn0, wm, wn, l15, lg, acc);

  const int sec = bn0 >> 10;   // 0=Q 1=K 2=V, uniform per block
  const int hh  = ((bn0 + wn) & 1023) >> 6;
  const int rw0 = bm0 + wm;
  const int bb  = rw0 >> 11, t00 = rw0 & 2047;
  const int bh  = bb * 16 + hh;

  if (sec < 2) {
    bf16* ep = ((wave < 2) ? lA : lB) + (wave & 1) * 4096;   // 64x64 bf16 per wave
#pragma unroll
    for (int i = 0; i < 4; ++i)
#pragma unroll
      for (int j = 0; j < 4; ++j) {
        const float bs = bias[bn0 + wn + j * 16 + l15];
        const int cj = j * 16 + l15;
#pragma unroll
        for (int r = 0; r < 4; ++r) {
          const int ri = i * 16 + 4 * lg + r;
          ep[ri * 64 + (cj ^ ((ri & 7) << 3))] = (bf16)(acc[i][j][r] + bs);
        }
      }
    __syncthreads();
    bf16* dstB = (sec ? Kh : Qh) + ((size_t)bh * TT + t00) * HDIM;
    const int seg = lane & 7;
#pragma unroll
    for (int k = 0; k < 8; ++k) {
      const int ri = k * 8 + (lane >> 3);
      bf16x8 v = *reinterpret_cast<const bf16x8*>(&ep[ri * 64 + ((seg ^ (ri & 7)) * 8)]);
      *reinterpret_cast<bf16x8*>(dstB + (size_t)ri * HDIM + seg * 8) = v;
    }
  } else {
#pragma unroll
    for (int i = 0; i < 4; ++i)
#pragma unroll
      for (int j = 0; j < 4; ++j) {
        const int col = bn0 + wn + j * 16 + l15;
        const float bs = bias[col];
        const int dd = col & 63;
        const int t0 = t00 + i * 16 + lg * 4;
        bf16x4 o4;
#pragma unroll
        for (int r = 0; r < 4; ++r) o4[r] = (bf16)(acc[i][j][r] + bs);
        *reinterpret_cast<bf16x4*>(VhT + ((size_t)bh * HDIM + dd) * TT + t0) = o4;
      }
  }
}

// ---------------- GEMM2: out = A @ W^T + b (fp32 out), XCD-tiled -------------------
__global__ __launch_bounds__(256) void gemm_bt(const bf16* __restrict__ A,
                                               const bf16* __restrict__ W,
                                               const float* __restrict__ bias,
                                               float* __restrict__ Cf,
                                               int M, int N, int K) {
  __shared__ __align__(16) bf16 lA[128 * 64];
  __shared__ __align__(16) bf16 lB[128 * 64];
  const int tid  = threadIdx.x;
  const int lane = tid & 63, wave = tid >> 6;
  const int wm   = (wave >> 1) * 64;
  const int wn   = (wave & 1) * 64;
  const int bidx = blockIdx.x;
  const int g  = bidx & 7;
  const int i_ = bidx >> 3;                 // 0..63
  const int bm0 = (g * 8 + (i_ & 7)) * 128;
  const int bn0 = (i_ >> 3) * 128;          // 0..7
  const int l15  = lane & 15, lg = lane >> 4;

  f32x4 acc[4][4] = {};
  gemm_core(A, W, lA, lB, K, bm0, bn0, wm, wn, l15, lg, acc);

#pragma unroll
  for (int i = 0; i < 4; ++i)
#pragma unroll
    for (int j = 0; j < 4; ++j) {
      int col = bn0 + wn + j * 16 + l15;
      float bs = bias[col];
#pragma unroll
      for (int r = 0; r < 4; ++r) {
        int row = bm0 + wm + i * 16 + lg * 4 + r;
        Cf[(size_t)row * N + col] = acc[i][j][r] + bs;
      }
    }
}

// ---------------- one 32q x 64kv attention tile (R10-verified math) ----------------
__device__ __forceinline__ void attn_tile(const char* kbase, const char* vbase,
                                          const bf16x8 (&qfr)[4], f32x16 (&oacc)[2],
                                          float& mrun, float& srun,
                                          const int kv0, const int q0w,
                                          const int l31, const int hi, const int swz) {
  f32x16 s0 = {}, s1 = {};
  __builtin_amdgcn_s_setprio(1);
#pragma unroll
  for (int dc = 0; dc < 4; ++dc) {
    bf16x8 kf = *reinterpret_cast<const bf16x8*>(
        kbase + l31 * 128 + (((2 * dc + hi) * 16) ^ swz));
    s0 = __builtin_amdgcn_mfma_f32_32x32x16_bf16(kf, qfr[dc], s0, 0, 0, 0);
  }
#pragma unroll
  for (int dc = 0; dc < 4; ++dc) {
    bf16x8 kf = *reinterpret_cast<const bf16x8*>(
        kbase + (32 + l31) * 128 + (((2 * dc + hi) * 16) ^ swz));
    s1 = __builtin_amdgcn_mfma_f32_32x32x16_bf16(kf, qfr[dc], s1, 0, 0, 0);
  }
  __builtin_amdgcn_s_setprio(0);

  if (kv0 + 63 > q0w) {
    const int qg = q0w + l31;
#pragma unroll
    for (int r = 0; r < 16; ++r) {
      const int kvb = kv0 + (r & 3) + 8 * (r >> 2) + 4 * hi;
      if (kvb > qg)      s0[r] = -3e38f;
      if (kvb + 32 > qg) s1[r] = -3e38f;
    }
  }

  float m8[8];
#pragma unroll
  for (int i = 0; i < 8; ++i)
    m8[i] = fmaxf(fmaxf(s0[i], s0[i + 8]), fmaxf(s1[i], s1[i + 8]));
#pragma unroll
  for (int st = 4; st > 0; st >>= 1)
#pragma unroll
    for (int i = 0; i < st; ++i) m8[i] = fmaxf(m8[i], m8[i + st]);
  float mx = fmaxf(m8[0], __shfl_xor(m8[0], 32));

  float mref = mrun;
  if (!__all(mx <= mrun + 8.0f)) {
    const float mnew = fmaxf(mrun, mx);
    const float corr = __builtin_amdgcn_exp2f(mrun - mnew);
    mrun = mnew; mref = mnew;
    srun *= corr;
#pragma unroll
    for (int r = 0; r < 16; ++r) { oacc[0][r] *= corr; oacc[1][r] *= corr; }
  }

  float psum = 0.0f;
#pragma unroll
  for (int r = 0; r < 16; ++r) {
    s0[r] = __builtin_amdgcn_exp2f(s0[r] - mref);
    s1[r] = __builtin_amdgcn_exp2f(s1[r] - mref);
    psum += s0[r] + s1[r];
  }
  srun += psum;

  upw pw[4];
#pragma unroll
  for (int cl = 0; cl < 2; ++cl) {
    {
      u32 a01 = pkbf(s0[8 * cl + 0], s0[8 * cl + 1]);
      u32 a23 = pkbf(s0[8 * cl + 2], s0[8 * cl + 3]);
      u32 b01 = pkbf(s0[8 * cl + 4], s0[8 * cl + 5]);
      u32 b23 = pkbf(s0[8 * cl + 6], s0[8 * cl + 7]);
      asm("v_permlane32_swap_b32 %0, %1" : "+v"(a01), "+v"(b01));
      asm("v_permlane32_swap_b32 %0, %1" : "+v"(a23), "+v"(b23));
      pw[cl].w[0] = a01; pw[cl].w[1] = a23; pw[cl].w[2] = b01; pw[cl].w[3] = b23;
    }
    {
      u32 a01 = pkbf(s1[8 * cl + 0], s1[8 * cl + 1]);
      u32 a23 = pkbf(s1[8 * cl + 2], s1[8 * cl + 3]);
      u32 b01 = pkbf(s1[8 * cl + 4], s1[8 * cl + 5]);
      u32 b23 = pkbf(s1[8 * cl + 6], s1[8 * cl + 7]);
      asm("v_permlane32_swap_b32 %0, %1" : "+v"(a01), "+v"(b01));
      asm("v_permlane32_swap_b32 %0, %1" : "+v"(a23), "+v"(b23));
      pw[2 + cl].w[0] = a01; pw[2 + cl].w[1] = a23; pw[2 + cl].w[2] = b01; pw[2 + cl].w[3] = b23;
    }
  }

  __builtin_amdgcn_s_setprio(1);
#pragma unroll
  for (int dh = 0; dh < 2; ++dh) {
    const char* vrow = vbase + (32 * dh + l31) * 256;
#pragma unroll
    for (int c = 0; c < 4; ++c) {
      bf16x8 vf = *reinterpret_cast<const bf16x8*>(vrow + (((2 * c + hi) * 16) ^ swz));
      oacc[dh] = __builtin_amdgcn_mfma_f32_32x32x16_bf16(vf, pw[c].v, oacc[dh], 0, 0, 0);
    }
  }
  __builtin_amdgcn_s_setprio(0);
}

// ---------------- causal flash attention: 8-wave band-split, KVBLK=128 (R20) -------
__global__ __launch_bounds__(512, 4) void attn_kernel(const bf16* __restrict__ Qh,
                                                      const bf16* __restrict__ Kh,
                                                      const bf16* __restrict__ VhT,
                                                      bf16* __restrict__ aout) {
  __shared__ __align__(16) bf16 lK[2][128 * 64];
  __shared__ __align__(16) bf16 lVT[2][64 * 128];
  const int tid  = threadIdx.x;
  const int lane = tid & 63, wave = tid >> 6;   // 0..7
  const int l31  = lane & 31;
  const int hi   = lane >> 5;
  const int bid  = blockIdx.x;              // 0..511
  const int bh   = bid & 63;
  const int p    = bid >> 6;                // 0..7
  const int qtH  = 15 - p, qtL = p;
  const int band = wave >> 2;               // 0 = H, 1 = L
  const int qt   = band ? qtL : qtH;
  const int q0w  = qt * 128 + (wave & 3) * 32;
  const int b    = bh >> 4, h = bh & 15;
  const size_t tb = (size_t)b * TT;
  const int swz  = (l31 & 7) << 4;

  const float QSCALE = 0.18033688011112042f;
  bf16x8 qfr[4];
  {
    const bf16* qrow = Qh + ((size_t)bh * TT + q0w + l31) * HDIM;
#pragma unroll
    for (int dc = 0; dc < 4; ++dc) {
      bf16x8 v = *reinterpret_cast<const bf16x8*>(qrow + dc * 16 + hi * 8);
      bf16x8 o;
#pragma unroll
      for (int j = 0; j < 8; ++j) o[j] = (bf16)((float)v[j] * QSCALE);
      qfr[dc] = o;
    }
  }

  f32x16 oacc[2] = {};
  float mrun = -3e38f, srun = 0.0f;

  const int r0 = tid >> 3;
  const int sg = tid & 7;
  const int segK = sg ^ (r0 & 7);
  const bf16* kS = Kh + ((size_t)bh * TT + r0) * HDIM + (size_t)segK * 8;
  bf16* kD0 = &lK[0][r0 * 64 + sg * 8];
  bf16* kD1 = &lK[0][(r0 + 64) * 64 + sg * 8];
  const int rv = tid >> 4;
  const int hs = (tid >> 3) & 1;
  const int jv = tid & 7;
  const int cv = jv ^ (rv & 7);
  const bf16* vS0 = VhT + ((size_t)bh * HDIM + rv) * TT + hs * 64 + (size_t)cv * 8;
  const bf16* vS1 = VhT + ((size_t)bh * HDIM + rv + 32) * TT + hs * 64 + (size_t)cv * 8;
  bf16* vD0 = &lVT[0][tid * 8];
  bf16* vD1 = &lVT[0][(tid + 512) * 8];
  const int lKsz = 128 * 64, lVsz = 64 * 128;

  const int nkvt = qtH + 1;

  gload_lds16(kS,             kD0);
  gload_lds16(kS + 64 * HDIM, kD1);
  gload_lds16(vS0,            vD0);
  gload_lds16(vS1,            vD1);
  __syncthreads();

  int cur = 0;
  for (int t = 0; t < nkvt; ++t) {
    if (t + 1 < nkvt) {
      const size_t kv = (size_t)(t + 1) * 128;
      const int bo = (cur ^ 1);
      gload_lds16(kS + kv * HDIM,        kD0 + bo * lKsz);
      gload_lds16(kS + (kv + 64) * HDIM, kD1 + bo * lKsz);
      gload_lds16(vS0 + kv,              vD0 + bo * lVsz);
      gload_lds16(vS1 + kv,              vD1 + bo * lVsz);
    }

#pragma unroll
    for (int s = 0; s < 2; ++s) {
      const int kv0 = t * 128 + s * 64;
      if (kv0 <= q0w + 31)
        attn_tile((const char*)&lK[cur][0] + s * 8192,
                  (const char*)&lVT[cur][0] + s * 128,
                  qfr, oacc, mrun, srun, kv0, q0w, l31, hi, swz);
    }

    __syncthreads();
    cur ^= 1;
  }

  {
    srun += __shfl_xor(srun, 32);
    const float inv = 1.0f / srun;
    const int q = q0w + l31;
    bf16* orow = aout + (tb + q) * (size_t)EMBED + h * HDIM;
#pragma unroll
    for (int dh = 0; dh < 2; ++dh)
#pragma unroll
      for (int rb = 0; rb < 4; ++rb) {
        bf16x4 o4;
#pragma unroll
        for (int k = 0; k < 4; ++k) o4[k] = (bf16)(oacc[dh][4 * rb + k] * inv);
        *reinterpret_cast<bf16x4*>(orow + 32 * dh + 8 * rb + 4 * hi) = o4;
      }
  }
}

extern "C" void kernel_launch(void* const* d_in, const int* in_sizes, int n_in,
                              void* d_out, int out_size, void* d_ws, size_t ws_size,
                              hipStream_t stream) {
  const float* x      = (const float*)d_in[0];
  const float* qkv_w  = (const float*)d_in[1];
  const float* qkv_b  = (const float*)d_in[2];
  const float* proj_w = (const float*)d_in[3];
  const float* proj_b = (const float*)d_in[4];
  float* out = (float*)d_out;

  const size_t QSZ = (size_t)BB * NHEAD * TT * HDIM;
  char* ws = (char*)d_ws;
  bf16* xb    = (bf16*)ws;
  bf16* wqkv  = xb + (size_t)MTOK * EMBED;
  bf16* wproj = wqkv + (size_t)C3 * EMBED;
  bf16* Qh    = wproj + (size_t)EMBED * EMBED;
  bf16* Kh    = Qh + QSZ;
  bf16* VhT   = Kh + QSZ;
  bf16* aob   = xb;   // alias: xb dead after gemm_qkv

  cvt_all<<<dim3(2048), dim3(256), 0, stream>>>(x, qkv_w, proj_w, xb, wqkv, wproj);

  gemm_qkv<<<dim3(1536), dim3(256), 0, stream>>>(xb, wqkv, qkv_b, Qh, Kh, VhT);

  attn_kernel<<<dim3(512), dim3(512), 0, stream>>>(Qh, Kh, VhT, aob);

  gemm_bt<<<dim3(512), dim3(256), 0, stream>>>(aob, wproj, proj_b, out,
                                               MTOK, EMBED, EMBED);
}